// Round 4
// baseline (805.880 us; speedup 1.0000x reference)
//
#include <hip/hip_runtime.h>

// Round 4 resubmission — rounds 1-3 died with UnresponsiveContainer before any
// compile/test; source unchanged since round 1 (desk-checked this round).

#define T_FRAMES 1001
#define NFREQ 201
#define FPB 8
#define MEL_STRIDE 1008

// ws layout (floats):
// [0)        ctab  [400][256] float2  -> 204800 floats
// [204800)   win   [400]
// [205200)   fbt   [201][64]          -> 12864
// [218064)   dct   [64][20]           -> 1280
// [219344)   mel   [4096][1008]       -> 4128768
#define OFF_WIN 204800
#define OFF_FB  205200
#define OFF_DCT 218064
#define OFF_MEL 219344

__device__ __forceinline__ int reflect_idx(int g) {
  g = (g < 0) ? -g : g;
  g = (g >= 160000) ? (319998 - g) : g;
  return g;
}

__device__ __forceinline__ float f4c(const float4& v, int k) {
  switch (k) { case 0: return v.x; case 1: return v.y; case 2: return v.z; default: return v.w; }
}

__global__ __launch_bounds__(256) void k_init(float* __restrict__ ws) {
  float2* ctab = (float2*)ws;
  float* win = ws + OFF_WIN;
  float* fbt = ws + OFF_FB;
  float* dct = ws + OFF_DCT;
  const float W = 6.28318530717958647692f / 400.0f;
  int tid = blockIdx.x * 256 + threadIdx.x;
  int stride = gridDim.x * 256;
  for (int i = tid; i < 102400; i += stride) {
    int n = i >> 8, f = i & 255;
    int p = (n * f) % 400;
    float a = (float)p * W;
    ctab[i] = make_float2(cosf(a), -sinf(a));
  }
  for (int i = tid; i < 400; i += stride) win[i] = 0.5f - 0.5f * cosf((float)i * W);
  for (int i = tid; i < NFREQ * 64; i += stride) {
    int f = i >> 6, m = i & 63;
    float freq = 40.0f * (float)f;
    float m_max = 2595.0f * log10f(1.0f + 8000.0f / 700.0f);
    float ms = m_max / 65.0f;
    float fp0 = 700.0f * (powf(10.0f, (float)(m)     * ms / 2595.0f) - 1.0f);
    float fp1 = 700.0f * (powf(10.0f, (float)(m + 1) * ms / 2595.0f) - 1.0f);
    float fp2 = 700.0f * (powf(10.0f, (float)(m + 2) * ms / 2595.0f) - 1.0f);
    float dn = (freq - fp0) / (fp1 - fp0);
    float up = (fp2 - freq) / (fp2 - fp1);
    fbt[i] = fmaxf(0.0f, fminf(dn, up));
  }
  for (int i = tid; i < 64 * 20; i += stride) {
    int m = i / 20, k = i % 20;
    float v = cosf(3.14159265358979323846f / 64.0f * ((float)m + 0.5f) * (float)k) * sqrtf(2.0f / 64.0f);
    if (k == 0) v *= 0.70710678118654752440f;
    dct[i] = v;
  }
}

// One wave per block. Handles FPB consecutive frames of one batch row.
// Each lane owns 4 freq bins (f = q*64+lane, padded to 256) x FPB frames.
__global__ __launch_bounds__(64) void k_dft_mel(const float* __restrict__ wav,
                                                const float* __restrict__ ws,
                                                float* __restrict__ mel) {
  __shared__ float xw[FPB][400];
  __shared__ float pw[256][FPB];
  const float2* __restrict__ ctab = (const float2*)ws;
  const float* __restrict__ win = ws + OFF_WIN;
  const float* __restrict__ fbt = ws + OFF_FB;
  int lane = threadIdx.x;
  int b = blockIdx.y;
  int t0 = blockIdx.x * FPB;
  int nf = min(FPB, T_FRAMES - t0);
  const float* wv = wav + (size_t)b * 160000;

  for (int j = 0; j < FPB; ++j) {
    for (int n = lane; n < 400; n += 64) {
      float v = 0.0f;
      if (j < nf) {
        int g = reflect_idx((t0 + j) * 160 + n - 200);
        v = wv[g] * win[n];
      }
      xw[j][n] = v;
    }
  }
  __syncthreads();

  float re[4][FPB], im[4][FPB];
#pragma unroll
  for (int q = 0; q < 4; ++q)
#pragma unroll
    for (int j = 0; j < FPB; ++j) { re[q][j] = 0.0f; im[q][j] = 0.0f; }

  for (int n4 = 0; n4 < 400; n4 += 4) {
    float4 xv[FPB];
#pragma unroll
    for (int j = 0; j < FPB; ++j) xv[j] = *(const float4*)&xw[j][n4];
#pragma unroll
    for (int dn = 0; dn < 4; ++dn) {
#pragma unroll
      for (int q = 0; q < 4; ++q) {
        float2 cs = ctab[((n4 + dn) << 8) + (q << 6) + lane];
        float c = cs.x, s = cs.y;
#pragma unroll
        for (int j = 0; j < FPB; ++j) {
          float x = f4c(xv[j], dn);
          re[q][j] = fmaf(x, c, re[q][j]);
          im[q][j] = fmaf(x, s, im[q][j]);
        }
      }
    }
  }

#pragma unroll
  for (int q = 0; q < 4; ++q) {
#pragma unroll
    for (int j = 0; j < FPB; ++j) {
      pw[(q << 6) + lane][j] = fmaf(re[q][j], re[q][j], im[q][j] * im[q][j]);
    }
  }
  __syncthreads();

  // mel projection: lane = mel index
  float acc[FPB];
#pragma unroll
  for (int j = 0; j < FPB; ++j) acc[j] = 0.0f;
  for (int f = 0; f < NFREQ; ++f) {
    float w = fbt[(f << 6) + lane];
    float4 p0 = *(const float4*)&pw[f][0];
    float4 p1 = *(const float4*)&pw[f][4];
    acc[0] = fmaf(w, p0.x, acc[0]);
    acc[1] = fmaf(w, p0.y, acc[1]);
    acc[2] = fmaf(w, p0.z, acc[2]);
    acc[3] = fmaf(w, p0.w, acc[3]);
    acc[4] = fmaf(w, p1.x, acc[4]);
    acc[5] = fmaf(w, p1.y, acc[5]);
    acc[6] = fmaf(w, p1.z, acc[6]);
    acc[7] = fmaf(w, p1.w, acc[7]);
  }
  size_t base = ((size_t)b * 64 + lane) * MEL_STRIDE + t0;
  for (int j = 0; j < nf; ++j) mel[base + j] = acc[j];
}

// One thread per (b, m) row: sequential EMA over t, writes mel_norm.
__global__ __launch_bounds__(256) void k_ema(const float* __restrict__ mel,
                                             float* __restrict__ outp) {
  int row = blockIdx.x * 256 + threadIdx.x;  // 0..4095
  const float* src = mel + (size_t)row * MEL_STRIDE;
  float* dst = outp + (size_t)row * 1001;
  float sm = 0.0f;
  float4 A = *(const float4*)&src[0];
  float4 Bv = *(const float4*)&src[4];
  for (int t4 = 0; t4 < 1000; t4 += 4) {
    float4 cur = A;
    A = Bv;
    Bv = *(const float4*)&src[t4 + 8];  // rows padded to 1008, always in-bounds
    sm = fmaf(0.98f, sm, 0.02f * cur.x); dst[t4 + 0] = log1pf(cur.x / (sm + 1e-6f));
    sm = fmaf(0.98f, sm, 0.02f * cur.y); dst[t4 + 1] = log1pf(cur.y / (sm + 1e-6f));
    sm = fmaf(0.98f, sm, 0.02f * cur.z); dst[t4 + 2] = log1pf(cur.z / (sm + 1e-6f));
    sm = fmaf(0.98f, sm, 0.02f * cur.w); dst[t4 + 3] = log1pf(cur.w / (sm + 1e-6f));
  }
  float x = A.x;  // t = 1000
  sm = fmaf(0.98f, sm, 0.02f * x);
  dst[1000] = log1pf(x / (sm + 1e-6f));
}

// mfcc[b][k][t] = sum_m 10*log10(max(mel,1e-10)) * DCT[m][k]
__global__ __launch_bounds__(256) void k_mfcc(const float* __restrict__ mel,
                                              const float* __restrict__ ws,
                                              float* __restrict__ outp) {
  __shared__ float dls[64 * 20];
  const float* dct = ws + OFF_DCT;
  for (int i = threadIdx.x; i < 64 * 20; i += 256) dls[i] = dct[i];
  __syncthreads();
  int b = blockIdx.y;
  int t = blockIdx.x * 256 + threadIdx.x;
  if (t >= T_FRAMES) return;
  float acc[20];
#pragma unroll
  for (int k = 0; k < 20; ++k) acc[k] = 0.0f;
  for (int m = 0; m < 64; ++m) {
    float v = mel[((size_t)b * 64 + m) * MEL_STRIDE + t];
    float db = 10.0f * log10f(fmaxf(v, 1e-10f));
#pragma unroll
    for (int k = 0; k < 20; ++k) acc[k] = fmaf(db, dls[m * 20 + k], acc[k]);
  }
  float* o = outp + (size_t)b * 20 * 1001 + t;
#pragma unroll
  for (int k = 0; k < 20; ++k) o[(size_t)k * 1001] = acc[k];
}

extern "C" void kernel_launch(void* const* d_in, const int* in_sizes, int n_in,
                              void* d_out, int out_size, void* d_ws, size_t ws_size,
                              hipStream_t stream) {
  const float* wav = (const float*)d_in[0];
  float* out = (float*)d_out;
  float* ws = (float*)d_ws;
  float* mel = ws + OFF_MEL;

  hipLaunchKernelGGL(k_init, dim3(64), dim3(256), 0, stream, ws);
  hipLaunchKernelGGL(k_dft_mel, dim3((T_FRAMES + FPB - 1) / FPB, 64), dim3(64), 0, stream,
                     wav, ws, mel);
  hipLaunchKernelGGL(k_ema, dim3(16), dim3(256), 0, stream, mel, out);
  hipLaunchKernelGGL(k_mfcc, dim3(4, 64), dim3(256), 0, stream, mel, ws, out + 4100096);
}

// Round 6
// 375.742 us; speedup vs baseline: 2.1448x; 2.1448x over previous
//
#include <hip/hip_runtime.h>

#define T_FRAMES 1001
#define MEL_STRIDE 1008

// ws float offsets
#define OFF_WIN 0        // [416] f32 (400 + zero pad)
#define OFF_DCT 416      // [64][20] f32
#define OFF_BG  1696     // u16[13 ktile][16384] twiddles, chunked layout (212992 u16)
#define OFF_FBG 108192   // u16[64 mel][264 k] (16896 u16)
#define OFF_MEL 116640   // f32[4096][1008]

typedef unsigned int u32;
typedef unsigned short u16;
typedef __attribute__((ext_vector_type(8))) short bf16x8;
typedef __attribute__((ext_vector_type(4))) float f32x4;

__device__ __forceinline__ u16 f2bf(float f) {
  u32 u = __float_as_uint(f);
  u32 r = (u + 0x7FFFu + ((u >> 16) & 1u)) >> 16;
  return (u16)r;
}

__device__ __forceinline__ int reflect_idx(int g) {
  g = (g < 0) ? -g : g;
  g = (g >= 160000) ? (319998 - g) : g;
  return g;
}

// async global->LDS: each of 64 lanes writes 16B at (uniform LDS base + lane*16)
__device__ __forceinline__ void g2l16(const void* g, void* l) {
  __builtin_amdgcn_global_load_lds(
      (const __attribute__((address_space(1))) u32*)(unsigned long long)g,
      (__attribute__((address_space(3))) u32*)(u32)(unsigned long long)l,
      16, 0, 0);
}

__global__ __launch_bounds__(256) void k_init(float* __restrict__ ws) {
  float* win = ws + OFF_WIN;
  float* dct = ws + OFF_DCT;
  u16* bg = (u16*)(ws + OFF_BG);
  u16* fbg = (u16*)(ws + OFF_FBG);
  const float W = 6.28318530717958647692f / 400.0f;
  int tid = blockIdx.x * 256 + threadIdx.x;
  int stride = gridDim.x * 256;
  for (int i = tid; i < 416; i += stride)
    win[i] = (i < 400) ? (0.5f - 0.5f * cosf((float)i * W)) : 0.0f;
  for (int i = tid; i < 64 * 20; i += stride) {
    int m = i / 20, k = i % 20;
    float v = cosf(3.14159265358979323846f / 64.0f * ((float)m + 0.5f) * (float)k) * sqrtf(2.0f / 64.0f);
    if (k == 0) v *= 0.70710678118654752440f;
    dct[i] = v;
  }
  // twiddles, chunked: u16 index = kt*16384 + g*512 + khalf*128 + c15*8 + e
  //   col = g*16+c15 (512 cols: alternating 16 re / 16 im per bin-group of 16)
  //   k within ktile = khalf*8 + e; n = kt*32 + k
  for (int i = tid; i < 13 * 16384; i += stride) {
    int kt = i >> 14;
    int r = i & 16383;
    int g = r >> 9;
    int khalf = (r >> 7) & 3;
    int c15 = (r >> 3) & 15;
    int e = r & 7;
    int col = g * 16 + c15;
    int n = kt * 32 + khalf * 8 + e;
    int bin = ((col >> 5) << 4) | (col & 15);
    int type = (col >> 4) & 1;
    float v = 0.0f;
    if (n < 400 && bin <= 200) {
      float a = (float)((n * bin) % 400) * W;
      v = type ? -sinf(a) : cosf(a);
    }
    bg[i] = f2bf(v);
  }
  // mel filterbank [mel][264 k], zero past bin 200
  for (int i = tid; i < 64 * 264; i += stride) {
    int m = i / 264, f = i % 264;
    float v = 0.0f;
    if (f <= 200) {
      float freq = 40.0f * (float)f;
      float m_max = 2595.0f * log10f(1.0f + 8000.0f / 700.0f);
      float ms = m_max / 65.0f;
      float fp0 = 700.0f * (powf(10.0f, (float)(m)     * ms / 2595.0f) - 1.0f);
      float fp1 = 700.0f * (powf(10.0f, (float)(m + 1) * ms / 2595.0f) - 1.0f);
      float fp2 = 700.0f * (powf(10.0f, (float)(m + 2) * ms / 2595.0f) - 1.0f);
      float dn = (freq - fp0) / (fp1 - fp0);
      float up = (fp2 - freq) / (fp2 - fp1);
      v = fmaxf(0.0f, fminf(dn, up));
    }
    fbg[i] = f2bf(v);
  }
}

// One block = 64 frames of one batch row; 4 waves.
// GEMM1: A[64x416] (windowed frames, bf16) x B[416x512] (twiddles) -> X re/im
// P = re^2+im^2 -> LDS (bf16); GEMM2: P[64x256] x FB[256x64] -> mel^T -> store.
// A/B LDS layout is fragment-chunked: every MFMA fragment read = base + lane*16
// (conflict-free, and B's chunk order == its global staging order).
__global__ __launch_bounds__(256, 1) void k_gemm(const float* __restrict__ wav,
                                                 const float* __restrict__ ws,
                                                 float* __restrict__ mel) {
  extern __shared__ char sm[];
  char* Ald8 = sm;              // 4 rowgroups x 13 kt x 1024B = 53248
  char* Bld = sm + 53248;       // 2 x 32768 dbuf; ktile = 32 chunks x 1024B
  const float* win = ws + OFF_WIN;
  const char* Bg = (const char*)(ws + OFF_BG);
  const char* FBg = (const char*)(ws + OFF_FBG);

  int tid = threadIdx.x;
  int wid = tid >> 6, lane = tid & 63;
  int bx = blockIdx.x, b = blockIdx.y;
  int t0 = bx * 64;
  const float* wv = wav + (size_t)b * 160000;

  // ---- A build: A[j][n] = wav[(t0+j)*160 + n - 200 (reflect)] * win[n] ----
  {
    int j = tid >> 2, q = tid & 3;
    int mi = j >> 4, r15 = j & 15;
    int sbase = (t0 + j) * 160 - 200;
    bool fast = (bx >= 1 && bx <= 14);  // whole 416-sample span in-bounds
    for (int c = 0; c < 13; ++c) {
      int n = q * 104 + c * 8;
      uint4 pk;
      if (n < 400) {
        float x0, x1, x2, x3, x4, x5, x6, x7;
        if (fast) {
          float4 a0 = *(const float4*)&wv[sbase + n];
          float4 a1 = *(const float4*)&wv[sbase + n + 4];
          x0 = a0.x; x1 = a0.y; x2 = a0.z; x3 = a0.w;
          x4 = a1.x; x5 = a1.y; x6 = a1.z; x7 = a1.w;
        } else {
          x0 = wv[reflect_idx(sbase + n)];
          x1 = wv[reflect_idx(sbase + n + 1)];
          x2 = wv[reflect_idx(sbase + n + 2)];
          x3 = wv[reflect_idx(sbase + n + 3)];
          x4 = wv[reflect_idx(sbase + n + 4)];
          x5 = wv[reflect_idx(sbase + n + 5)];
          x6 = wv[reflect_idx(sbase + n + 6)];
          x7 = wv[reflect_idx(sbase + n + 7)];
        }
        const float* w = &win[n];
        pk.x = (u32)f2bf(x0 * w[0]) | ((u32)f2bf(x1 * w[1]) << 16);
        pk.y = (u32)f2bf(x2 * w[2]) | ((u32)f2bf(x3 * w[3]) << 16);
        pk.z = (u32)f2bf(x4 * w[4]) | ((u32)f2bf(x5 * w[5]) << 16);
        pk.w = (u32)f2bf(x6 * w[6]) | ((u32)f2bf(x7 * w[7]) << 16);
      } else {
        pk = make_uint4(0, 0, 0, 0);
      }
      int kt = n >> 5, khalf = (n >> 3) & 3;
      *(uint4*)(Ald8 + (mi * 13 + kt) * 1024 + khalf * 256 + r15 * 16) = pk;
    }
  }

  // stage B ktile 0 into buf0
  for (int i = wid; i < 32; i += 4)
    g2l16(Bg + i * 1024 + lane * 16, Bld + i * 1024);
  __syncthreads();

  // ---- GEMM1: wave w owns cols [w*128, w*128+128) ----
  f32x4 acc[4][8];
  const f32x4 zf = {0.0f, 0.0f, 0.0f, 0.0f};
#pragma unroll
  for (int mi = 0; mi < 4; ++mi)
#pragma unroll
    for (int nf = 0; nf < 8; ++nf) acc[mi][nf] = zf;

  for (int kt = 0; kt < 13; ++kt) {
    if (kt + 1 < 13) {
      const char* src = Bg + (kt + 1) * 32768;
      char* dst = Bld + ((kt + 1) & 1) * 32768;
      for (int i = wid; i < 32; i += 4)
        g2l16(src + i * 1024 + lane * 16, dst + i * 1024);
    }
    const char* Bt = Bld + (kt & 1) * 32768;
    bf16x8 af[4], bfr[8];
#pragma unroll
    for (int mi = 0; mi < 4; ++mi)
      af[mi] = *(const bf16x8*)(Ald8 + (mi * 13 + kt) * 1024 + lane * 16);
#pragma unroll
    for (int nf = 0; nf < 8; ++nf)
      bfr[nf] = *(const bf16x8*)(Bt + (wid * 8 + nf) * 1024 + lane * 16);
#pragma unroll
    for (int mi = 0; mi < 4; ++mi)
#pragma unroll
      for (int nf = 0; nf < 8; ++nf)
        acc[mi][nf] = __builtin_amdgcn_mfma_f32_16x16x32_bf16(af[mi], bfr[nf], acc[mi][nf], 0, 0, 0);
    __syncthreads();
  }

  // ---- P = re^2+im^2 (bf16) into B region; stage FB into A region ----
  u16* Pld = (u16*)(sm + 53248);  // [64 frame][264 bin]
  u16* FBld = (u16*)sm;           // [64 mel][264 bin]
  for (int i = wid; i < 33; i += 4)
    g2l16(FBg + i * 1024 + lane * 16, (char*)FBld + i * 1024);
#pragma unroll
  for (int mi = 0; mi < 4; ++mi)
#pragma unroll
    for (int i = 0; i < 4; ++i)
#pragma unroll
      for (int r = 0; r < 4; ++r) {
        int row = mi * 16 + (lane >> 4) * 4 + r;          // frame
        int bin = wid * 64 + i * 16 + (lane & 15);        // freq bin
        float re = acc[mi][2 * i][r], im = acc[mi][2 * i + 1][r];
        Pld[row * 264 + bin] = f2bf(re * re + im * im);
      }
  __syncthreads();

  // ---- GEMM2: wave w owns frame rows [w*16, w*16+16), all 64 mels ----
  f32x4 macc[4];
#pragma unroll
  for (int nf = 0; nf < 4; ++nf) macc[nf] = zf;
  for (int kt = 0; kt < 8; ++kt) {
    int krow = kt * 32 + (lane >> 4) * 8;
    bf16x8 pa = *(const bf16x8*)&Pld[(wid * 16 + (lane & 15)) * 264 + krow];
#pragma unroll
    for (int nf = 0; nf < 4; ++nf) {
      bf16x8 pb = *(const bf16x8*)&FBld[(nf * 16 + (lane & 15)) * 264 + krow];
      macc[nf] = __builtin_amdgcn_mfma_f32_16x16x32_bf16(pa, pb, macc[nf], 0, 0, 0);
    }
  }
  __syncthreads();

  // ---- transpose via LDS, coalesced store ----
  float* Tld = (float*)(sm + 53248);  // [64 mel][68]
#pragma unroll
  for (int nf = 0; nf < 4; ++nf)
#pragma unroll
    for (int r = 0; r < 4; ++r) {
      int m = nf * 16 + (lane & 15);
      int tr = wid * 16 + (lane >> 4) * 4 + r;
      Tld[m * 68 + tr] = macc[nf][r];
    }
  __syncthreads();

  for (int i = tid; i < 1024; i += 256) {
    int m = i >> 4, qd = i & 15;
    int t = t0 + qd * 4;
    float4 v = *(const float4*)&Tld[m * 68 + qd * 4];
    float* dst = mel + ((size_t)b * 64 + m) * MEL_STRIDE + t;
    if (t + 3 <= 1000) {
      *(float4*)dst = v;
    } else {
      if (t     <= 1000) dst[0] = v.x;
      if (t + 1 <= 1000) dst[1] = v.y;
      if (t + 2 <= 1000) dst[2] = v.z;
      if (t + 3 <= 1000) dst[3] = v.w;
    }
  }
}

// One thread per (b, m) row: sequential EMA over t, writes mel_norm.
__global__ __launch_bounds__(64) void k_ema(const float* __restrict__ mel,
                                            float* __restrict__ outp) {
  int row = blockIdx.x * 64 + threadIdx.x;  // 0..4095
  const float* src = mel + (size_t)row * MEL_STRIDE;
  float* dst = outp + (size_t)row * 1001;
  float smv = 0.0f;
  float4 A = *(const float4*)&src[0];
  float4 Bv = *(const float4*)&src[4];
  for (int t4 = 0; t4 < 1000; t4 += 4) {
    float4 cur = A;
    A = Bv;
    Bv = *(const float4*)&src[t4 + 8];  // rows padded to 1008, always in-bounds
    smv = fmaf(0.98f, smv, 0.02f * cur.x); dst[t4 + 0] = log1pf(cur.x / (smv + 1e-6f));
    smv = fmaf(0.98f, smv, 0.02f * cur.y); dst[t4 + 1] = log1pf(cur.y / (smv + 1e-6f));
    smv = fmaf(0.98f, smv, 0.02f * cur.z); dst[t4 + 2] = log1pf(cur.z / (smv + 1e-6f));
    smv = fmaf(0.98f, smv, 0.02f * cur.w); dst[t4 + 3] = log1pf(cur.w / (smv + 1e-6f));
  }
  float x = A.x;  // t = 1000
  smv = fmaf(0.98f, smv, 0.02f * x);
  dst[1000] = log1pf(x / (smv + 1e-6f));
}

// mfcc[b][k][t] = sum_m 10*log10(max(mel,1e-10)) * DCT[m][k]
__global__ __launch_bounds__(256) void k_mfcc(const float* __restrict__ mel,
                                              const float* __restrict__ ws,
                                              float* __restrict__ outp) {
  __shared__ float dls[64 * 20];
  const float* dct = ws + OFF_DCT;
  for (int i = threadIdx.x; i < 64 * 20; i += 256) dls[i] = dct[i];
  __syncthreads();
  int b = blockIdx.y;
  int t = blockIdx.x * 256 + threadIdx.x;
  if (t >= T_FRAMES) return;
  float acc[20];
#pragma unroll
  for (int k = 0; k < 20; ++k) acc[k] = 0.0f;
  for (int m = 0; m < 64; ++m) {
    float v = mel[((size_t)b * 64 + m) * MEL_STRIDE + t];
    float db = 10.0f * log10f(fmaxf(v, 1e-10f));
#pragma unroll
    for (int k = 0; k < 20; ++k) acc[k] = fmaf(db, dls[m * 20 + k], acc[k]);
  }
  float* o = outp + (size_t)b * 20 * 1001 + t;
#pragma unroll
  for (int k = 0; k < 20; ++k) o[(size_t)k * 1001] = acc[k];
}

extern "C" void kernel_launch(void* const* d_in, const int* in_sizes, int n_in,
                              void* d_out, int out_size, void* d_ws, size_t ws_size,
                              hipStream_t stream) {
  const float* wav = (const float*)d_in[0];
  float* out = (float*)d_out;
  float* ws = (float*)d_ws;
  float* mel = ws + OFF_MEL;

  hipFuncSetAttribute(reinterpret_cast<const void*>(k_gemm),
                      hipFuncAttributeMaxDynamicSharedMemorySize, 118784);

  hipLaunchKernelGGL(k_init, dim3(64), dim3(256), 0, stream, ws);
  hipLaunchKernelGGL(k_gemm, dim3(16, 64), dim3(256), 118784, stream, wav, ws, mel);
  hipLaunchKernelGGL(k_ema, dim3(64), dim3(64), 0, stream, mel, out);
  hipLaunchKernelGGL(k_mfcc, dim3(4, 64), dim3(256), 0, stream, mel, ws, out + 4100096);
}

// Round 7
// 152.387 us; speedup vs baseline: 5.2884x; 2.4657x over previous
//
#include <hip/hip_runtime.h>

#define T_FRAMES 1001
#define MEL_STRIDE 1008

// ws float offsets
#define OFF_WIN 0        // [416] f32 (400 + zero pad)
#define OFF_DCT 416      // [64][20] f32
#define OFF_BG  1696     // u16[13 ktile][16384] twiddles, chunked layout (212992 u16)
#define OFF_FBG 108192   // u16[64 mel][264 k] (16896 u16)
#define OFF_MEL 116640   // f32[4096][1008]

typedef unsigned int u32;
typedef unsigned short u16;
typedef __attribute__((ext_vector_type(8))) short bf16x8;
typedef __attribute__((ext_vector_type(4))) float f32x4;

__device__ __forceinline__ u16 f2bf(float f) {
  u32 u = __float_as_uint(f);
  u32 r = (u + 0x7FFFu + ((u >> 16) & 1u)) >> 16;
  return (u16)r;
}

__device__ __forceinline__ int reflect_idx(int g) {
  g = (g < 0) ? -g : g;
  g = (g >= 160000) ? (319998 - g) : g;
  return g;
}

// async global->LDS: each of 64 lanes writes 16B at (uniform LDS base + lane*16)
__device__ __forceinline__ void g2l16(const void* g, void* l) {
  __builtin_amdgcn_global_load_lds(
      (const __attribute__((address_space(1))) u32*)(unsigned long long)g,
      (__attribute__((address_space(3))) u32*)(u32)(unsigned long long)l,
      16, 0, 0);
}

__global__ __launch_bounds__(256) void k_init(float* __restrict__ ws) {
  float* win = ws + OFF_WIN;
  float* dct = ws + OFF_DCT;
  u16* bg = (u16*)(ws + OFF_BG);
  u16* fbg = (u16*)(ws + OFF_FBG);
  const float W = 6.28318530717958647692f / 400.0f;
  int tid = blockIdx.x * 256 + threadIdx.x;
  int stride = gridDim.x * 256;
  for (int i = tid; i < 416; i += stride)
    win[i] = (i < 400) ? (0.5f - 0.5f * cosf((float)i * W)) : 0.0f;
  for (int i = tid; i < 64 * 20; i += stride) {
    int m = i / 20, k = i % 20;
    float v = cosf(3.14159265358979323846f / 64.0f * ((float)m + 0.5f) * (float)k) * sqrtf(2.0f / 64.0f);
    if (k == 0) v *= 0.70710678118654752440f;
    dct[i] = v;
  }
  // twiddles, chunked: u16 index = kt*16384 + g*512 + khalf*128 + c15*8 + e
  //   col = g*16+c15 (512 cols: alternating 16 re / 16 im per bin-group of 16)
  //   k within ktile = khalf*8 + e; n = kt*32 + k
  for (int i = tid; i < 13 * 16384; i += stride) {
    int kt = i >> 14;
    int r = i & 16383;
    int g = r >> 9;
    int khalf = (r >> 7) & 3;
    int c15 = (r >> 3) & 15;
    int e = r & 7;
    int col = g * 16 + c15;
    int n = kt * 32 + khalf * 8 + e;
    int bin = ((col >> 5) << 4) | (col & 15);
    int type = (col >> 4) & 1;
    float v = 0.0f;
    if (n < 400 && bin <= 200) {
      float a = (float)((n * bin) % 400) * W;
      v = type ? -sinf(a) : cosf(a);
    }
    bg[i] = f2bf(v);
  }
  // mel filterbank [mel][264 k], zero past bin 200
  for (int i = tid; i < 64 * 264; i += stride) {
    int m = i / 264, f = i % 264;
    float v = 0.0f;
    if (f <= 200) {
      float freq = 40.0f * (float)f;
      float m_max = 2595.0f * log10f(1.0f + 8000.0f / 700.0f);
      float ms = m_max / 65.0f;
      float fp0 = 700.0f * (powf(10.0f, (float)(m)     * ms / 2595.0f) - 1.0f);
      float fp1 = 700.0f * (powf(10.0f, (float)(m + 1) * ms / 2595.0f) - 1.0f);
      float fp2 = 700.0f * (powf(10.0f, (float)(m + 2) * ms / 2595.0f) - 1.0f);
      float dn = (freq - fp0) / (fp1 - fp0);
      float up = (fp2 - freq) / (fp2 - fp1);
      v = fmaxf(0.0f, fminf(dn, up));
    }
    fbg[i] = f2bf(v);
  }
}

// One block = 64 frames of one batch row; 4 waves.
// GEMM1: A[64x416] (windowed frames, bf16) x B[416x512] (twiddles) -> X re/im
// P = re^2+im^2 -> LDS (bf16); GEMM2: P[64x256] x FB[256x64] -> mel^T -> store.
// A/B LDS layout is fragment-chunked: every MFMA fragment read = base + lane*16
// (conflict-free, and B's chunk order == its global staging order).
__global__ __launch_bounds__(256, 1) void k_gemm(const float* __restrict__ wav,
                                                 const float* __restrict__ ws,
                                                 float* __restrict__ mel) {
  extern __shared__ char sm[];
  char* Ald8 = sm;              // 4 rowgroups x 13 kt x 1024B = 53248
  char* Bld = sm + 53248;       // 2 x 32768 dbuf; ktile = 32 chunks x 1024B
  const float* win = ws + OFF_WIN;
  const char* Bg = (const char*)(ws + OFF_BG);
  const char* FBg = (const char*)(ws + OFF_FBG);

  int tid = threadIdx.x;
  int wid = tid >> 6, lane = tid & 63;
  int bx = blockIdx.x, b = blockIdx.y;
  int t0 = bx * 64;
  const float* wv = wav + (size_t)b * 160000;

  // ---- A build: A[j][n] = wav[(t0+j)*160 + n - 200 (reflect)] * win[n] ----
  {
    int j = tid >> 2, q = tid & 3;
    int mi = j >> 4, r15 = j & 15;
    int sbase = (t0 + j) * 160 - 200;
    bool fast = (bx >= 1 && bx <= 14);  // whole 416-sample span in-bounds
    for (int c = 0; c < 13; ++c) {
      int n = q * 104 + c * 8;
      uint4 pk;
      if (n < 400) {
        float x0, x1, x2, x3, x4, x5, x6, x7;
        if (fast) {
          float4 a0 = *(const float4*)&wv[sbase + n];
          float4 a1 = *(const float4*)&wv[sbase + n + 4];
          x0 = a0.x; x1 = a0.y; x2 = a0.z; x3 = a0.w;
          x4 = a1.x; x5 = a1.y; x6 = a1.z; x7 = a1.w;
        } else {
          x0 = wv[reflect_idx(sbase + n)];
          x1 = wv[reflect_idx(sbase + n + 1)];
          x2 = wv[reflect_idx(sbase + n + 2)];
          x3 = wv[reflect_idx(sbase + n + 3)];
          x4 = wv[reflect_idx(sbase + n + 4)];
          x5 = wv[reflect_idx(sbase + n + 5)];
          x6 = wv[reflect_idx(sbase + n + 6)];
          x7 = wv[reflect_idx(sbase + n + 7)];
        }
        const float* w = &win[n];
        pk.x = (u32)f2bf(x0 * w[0]) | ((u32)f2bf(x1 * w[1]) << 16);
        pk.y = (u32)f2bf(x2 * w[2]) | ((u32)f2bf(x3 * w[3]) << 16);
        pk.z = (u32)f2bf(x4 * w[4]) | ((u32)f2bf(x5 * w[5]) << 16);
        pk.w = (u32)f2bf(x6 * w[6]) | ((u32)f2bf(x7 * w[7]) << 16);
      } else {
        pk = make_uint4(0, 0, 0, 0);
      }
      int kt = n >> 5, khalf = (n >> 3) & 3;
      *(uint4*)(Ald8 + (mi * 13 + kt) * 1024 + khalf * 256 + r15 * 16) = pk;
    }
  }

  // stage B ktile 0 into buf0
  for (int i = wid; i < 32; i += 4)
    g2l16(Bg + i * 1024 + lane * 16, Bld + i * 1024);
  __syncthreads();

  // ---- GEMM1: wave w owns cols [w*128, w*128+128) ----
  f32x4 acc[4][8];
  const f32x4 zf = {0.0f, 0.0f, 0.0f, 0.0f};
#pragma unroll
  for (int mi = 0; mi < 4; ++mi)
#pragma unroll
    for (int nf = 0; nf < 8; ++nf) acc[mi][nf] = zf;

  for (int kt = 0; kt < 13; ++kt) {
    if (kt + 1 < 13) {
      const char* src = Bg + (kt + 1) * 32768;
      char* dst = Bld + ((kt + 1) & 1) * 32768;
      for (int i = wid; i < 32; i += 4)
        g2l16(src + i * 1024 + lane * 16, dst + i * 1024);
    }
    const char* Bt = Bld + (kt & 1) * 32768;
    bf16x8 af[4], bfr[8];
#pragma unroll
    for (int mi = 0; mi < 4; ++mi)
      af[mi] = *(const bf16x8*)(Ald8 + (mi * 13 + kt) * 1024 + lane * 16);
#pragma unroll
    for (int nf = 0; nf < 8; ++nf)
      bfr[nf] = *(const bf16x8*)(Bt + (wid * 8 + nf) * 1024 + lane * 16);
#pragma unroll
    for (int mi = 0; mi < 4; ++mi)
#pragma unroll
      for (int nf = 0; nf < 8; ++nf)
        acc[mi][nf] = __builtin_amdgcn_mfma_f32_16x16x32_bf16(af[mi], bfr[nf], acc[mi][nf], 0, 0, 0);
    __syncthreads();
  }

  // ---- P = re^2+im^2 (bf16) into B region; stage FB into A region ----
  u16* Pld = (u16*)(sm + 53248);  // [64 frame][264 bin]
  u16* FBld = (u16*)sm;           // [64 mel][264 bin]
  for (int i = wid; i < 33; i += 4)
    g2l16(FBg + i * 1024 + lane * 16, (char*)FBld + i * 1024);
#pragma unroll
  for (int mi = 0; mi < 4; ++mi)
#pragma unroll
    for (int i = 0; i < 4; ++i)
#pragma unroll
      for (int r = 0; r < 4; ++r) {
        int row = mi * 16 + (lane >> 4) * 4 + r;          // frame
        int bin = wid * 64 + i * 16 + (lane & 15);        // freq bin
        float re = acc[mi][2 * i][r], im = acc[mi][2 * i + 1][r];
        Pld[row * 264 + bin] = f2bf(re * re + im * im);
      }
  __syncthreads();

  // ---- GEMM2: wave w owns frame rows [w*16, w*16+16), all 64 mels ----
  f32x4 macc[4];
#pragma unroll
  for (int nf = 0; nf < 4; ++nf) macc[nf] = zf;
  for (int kt = 0; kt < 8; ++kt) {
    int krow = kt * 32 + (lane >> 4) * 8;
    bf16x8 pa = *(const bf16x8*)&Pld[(wid * 16 + (lane & 15)) * 264 + krow];
#pragma unroll
    for (int nf = 0; nf < 4; ++nf) {
      bf16x8 pb = *(const bf16x8*)&FBld[(nf * 16 + (lane & 15)) * 264 + krow];
      macc[nf] = __builtin_amdgcn_mfma_f32_16x16x32_bf16(pa, pb, macc[nf], 0, 0, 0);
    }
  }
  __syncthreads();

  // ---- transpose via LDS, coalesced store ----
  float* Tld = (float*)(sm + 53248);  // [64 mel][68]
#pragma unroll
  for (int nf = 0; nf < 4; ++nf)
#pragma unroll
    for (int r = 0; r < 4; ++r) {
      int m = nf * 16 + (lane & 15);
      int tr = wid * 16 + (lane >> 4) * 4 + r;
      Tld[m * 68 + tr] = macc[nf][r];
    }
  __syncthreads();

  for (int i = tid; i < 1024; i += 256) {
    int m = i >> 4, qd = i & 15;
    int t = t0 + qd * 4;
    float4 v = *(const float4*)&Tld[m * 68 + qd * 4];
    float* dst = mel + ((size_t)b * 64 + m) * MEL_STRIDE + t;
    if (t + 3 <= 1000) {
      *(float4*)dst = v;
    } else {
      if (t     <= 1000) dst[0] = v.x;
      if (t + 1 <= 1000) dst[1] = v.y;
      if (t + 2 <= 1000) dst[2] = v.z;
      if (t + 3 <= 1000) dst[3] = v.w;
    }
  }
}

// Wave-parallel EMA: one wave per (b,m) row. Each lane owns 16 consecutive
// timesteps; affine maps (A,B) composed by a 6-step shuffle scan.
__global__ __launch_bounds__(256) void k_ema(const float* __restrict__ mel,
                                             float* __restrict__ outp) {
  int wid = threadIdx.x >> 6, lane = threadIdx.x & 63;
  int row = blockIdx.x * 4 + wid;  // 0..4095
  const float* src = mel + (size_t)row * MEL_STRIDE + lane * 16;

  float x[16];
  if (lane < 63) {  // lane 63 spans t>=1008 (past row stride): contributes zeros
    float4 v0 = *(const float4*)&src[0];
    float4 v1 = *(const float4*)&src[4];
    float4 v2 = *(const float4*)&src[8];
    float4 v3 = *(const float4*)&src[12];
    x[0] = v0.x; x[1] = v0.y; x[2] = v0.z; x[3] = v0.w;
    x[4] = v1.x; x[5] = v1.y; x[6] = v1.z; x[7] = v1.w;
    x[8] = v2.x; x[9] = v2.y; x[10] = v2.z; x[11] = v2.w;
    x[12] = v3.x; x[13] = v3.y; x[14] = v3.z; x[15] = v3.w;
#pragma unroll
    for (int i = 0; i < 16; ++i)
      if (lane * 16 + i > 1000) x[i] = 0.0f;  // stride pad: never stored, keep exact
  } else {
#pragma unroll
    for (int i = 0; i < 16; ++i) x[i] = 0.0f;
  }

  // local affine map of this 16-chunk: s_out = A*s_in + B
  float B = 0.0f;
#pragma unroll
  for (int i = 0; i < 16; ++i) B = fmaf(0.98f, B, 0.02f * x[i]);
  float A = 1.0f;
#pragma unroll
  for (int i = 0; i < 16; ++i) A *= 0.98f;  // constant-folded 0.98^16

  // inclusive scan of map composition across lanes (earlier = lower lane)
#pragma unroll
  for (int d = 1; d < 64; d <<= 1) {
    float Ap = __shfl_up(A, d, 64);
    float Bp = __shfl_up(B, d, 64);
    if (lane >= d) {
      B = fmaf(A, Bp, B);
      A = A * Ap;
    }
  }
  // incoming state for this lane = inclusive result of previous lane
  float s = __shfl_up(B, 1, 64);
  if (lane == 0) s = 0.0f;

  // re-walk with true incoming state
  float* dst = outp + (size_t)row * 1001 + lane * 16;
#pragma unroll
  for (int i = 0; i < 16; ++i) {
    s = fmaf(0.98f, s, 0.02f * x[i]);
    if (lane * 16 + i <= 1000) dst[i] = log1pf(x[i] / (s + 1e-6f));
  }
}

// mfcc[b][k][t] = sum_m 10*log10(max(mel,1e-10)) * DCT[m][k]
__global__ __launch_bounds__(256) void k_mfcc(const float* __restrict__ mel,
                                              const float* __restrict__ ws,
                                              float* __restrict__ outp) {
  __shared__ float dls[64 * 20];
  const float* dct = ws + OFF_DCT;
  for (int i = threadIdx.x; i < 64 * 20; i += 256) dls[i] = dct[i];
  __syncthreads();
  int b = blockIdx.y;
  int t = blockIdx.x * 256 + threadIdx.x;
  if (t >= T_FRAMES) return;
  float acc[20];
#pragma unroll
  for (int k = 0; k < 20; ++k) acc[k] = 0.0f;
  for (int m = 0; m < 64; ++m) {
    float v = mel[((size_t)b * 64 + m) * MEL_STRIDE + t];
    float db = 10.0f * log10f(fmaxf(v, 1e-10f));
#pragma unroll
    for (int k = 0; k < 20; ++k) acc[k] = fmaf(db, dls[m * 20 + k], acc[k]);
  }
  float* o = outp + (size_t)b * 20 * 1001 + t;
#pragma unroll
  for (int k = 0; k < 20; ++k) o[(size_t)k * 1001] = acc[k];
}

extern "C" void kernel_launch(void* const* d_in, const int* in_sizes, int n_in,
                              void* d_out, int out_size, void* d_ws, size_t ws_size,
                              hipStream_t stream) {
  const float* wav = (const float*)d_in[0];
  float* out = (float*)d_out;
  float* ws = (float*)d_ws;
  float* mel = ws + OFF_MEL;

  hipFuncSetAttribute(reinterpret_cast<const void*>(k_gemm),
                      hipFuncAttributeMaxDynamicSharedMemorySize, 118784);

  hipLaunchKernelGGL(k_init, dim3(64), dim3(256), 0, stream, ws);
  hipLaunchKernelGGL(k_gemm, dim3(16, 64), dim3(256), 118784, stream, wav, ws, mel);
  hipLaunchKernelGGL(k_ema, dim3(1024), dim3(256), 0, stream, mel, out);
  hipLaunchKernelGGL(k_mfcc, dim3(4, 64), dim3(256), 0, stream, mel, ws, out + 4100096);
}

// Round 9
// 149.017 us; speedup vs baseline: 5.4080x; 1.0226x over previous
//
#include <hip/hip_runtime.h>

#define T_FRAMES 1001
#define MEL_STRIDE 1008

// ws float offsets
#define OFF_WIN 0          // [416] f32
#define OFF_DCT 416        // [64][20] f32
#define OFF_BG  1696       // u16[13 ktile][16384] twiddles, chunked (106496 f)
#define OFF_FBG 108192     // u16[64 mel][264] (8448 f)
#define OFF_AG  116640     // bf16 [64 b][1024 fr][416] windowed frames (13631488 f)
#define OFF_MEL 13748128   // f32 [4096][1008]

typedef unsigned int u32;
typedef unsigned short u16;
typedef __attribute__((ext_vector_type(8))) short bf16x8;
typedef __attribute__((ext_vector_type(4))) float f32x4;

__device__ __forceinline__ u16 f2bf(float f) {
  u32 u = __float_as_uint(f);
  u32 r = (u + 0x7FFFu + ((u >> 16) & 1u)) >> 16;
  return (u16)r;
}

__device__ __forceinline__ int reflect_idx(int g) {
  g = (g < 0) ? -g : g;
  g = (g >= 160000) ? (319998 - g) : g;
  return g;
}

// async global->LDS: 64 lanes x 16B; src per-lane, dest = uniform base + lane*16
__device__ __forceinline__ void g2l16(const void* g, void* l) {
  __builtin_amdgcn_global_load_lds(
      (const __attribute__((address_space(1))) u32*)(unsigned long long)g,
      (__attribute__((address_space(3))) u32*)(u32)(unsigned long long)l,
      16, 0, 0);
}

__global__ __launch_bounds__(256) void k_init(float* __restrict__ ws) {
  float* win = ws + OFF_WIN;
  float* dct = ws + OFF_DCT;
  u16* bg = (u16*)(ws + OFF_BG);
  u16* fbg = (u16*)(ws + OFF_FBG);
  const float W = 6.28318530717958647692f / 400.0f;
  int tid = blockIdx.x * 256 + threadIdx.x;
  int stride = gridDim.x * 256;
  for (int i = tid; i < 416; i += stride)
    win[i] = (i < 400) ? (0.5f - 0.5f * cosf((float)i * W)) : 0.0f;
  for (int i = tid; i < 64 * 20; i += stride) {
    int m = i / 20, k = i % 20;
    float v = cosf(3.14159265358979323846f / 64.0f * ((float)m + 0.5f) * (float)k) * sqrtf(2.0f / 64.0f);
    if (k == 0) v *= 0.70710678118654752440f;
    dct[i] = v;
  }
  // twiddles, chunked: u16 index = kt*16384 + g*512 + khalf*128 + c15*8 + e
  for (int i = tid; i < 13 * 16384; i += stride) {
    int kt = i >> 14;
    int r = i & 16383;
    int g = r >> 9;
    int khalf = (r >> 7) & 3;
    int c15 = (r >> 3) & 15;
    int e = r & 7;
    int col = g * 16 + c15;
    int n = kt * 32 + khalf * 8 + e;
    int bin = ((col >> 5) << 4) | (col & 15);
    int type = (col >> 4) & 1;
    float v = 0.0f;
    if (n < 400 && bin <= 200) {
      float a = (float)((n * bin) % 400) * W;
      v = type ? -sinf(a) : cosf(a);
    }
    bg[i] = f2bf(v);
  }
  // mel filterbank [mel][264], zero past bin 200
  for (int i = tid; i < 64 * 264; i += stride) {
    int m = i / 264, f = i % 264;
    float v = 0.0f;
    if (f <= 200) {
      float freq = 40.0f * (float)f;
      float m_max = 2595.0f * log10f(1.0f + 8000.0f / 700.0f);
      float ms = m_max / 65.0f;
      float fp0 = 700.0f * (powf(10.0f, (float)(m)     * ms / 2595.0f) - 1.0f);
      float fp1 = 700.0f * (powf(10.0f, (float)(m + 1) * ms / 2595.0f) - 1.0f);
      float fp2 = 700.0f * (powf(10.0f, (float)(m + 2) * ms / 2595.0f) - 1.0f);
      float dn = (freq - fp0) / (fp1 - fp0);
      float up = (fp2 - freq) / (fp2 - fp1);
      v = fmaxf(0.0f, fminf(dn, up));
    }
    fbg[i] = f2bf(v);
  }
}

// Precompute windowed frames: AG[b][fr][n] = wav[b][fr*160+n-200 (reflect)]*win[n]
// bf16, rows padded to 1024 frames/batch (frames >1000 = zeros).
__global__ __launch_bounds__(256) void k_prep(const float* __restrict__ wav,
                                              const float* __restrict__ ws,
                                              u16* __restrict__ AG) {
  int idx = blockIdx.x * 256 + threadIdx.x;  // < 64*1024*52
  int c = idx % 52;
  int rowi = idx / 52;                        // b*1024 + fr
  int fr = rowi & 1023;
  int n0 = c * 8;
  uint4 pk = make_uint4(0, 0, 0, 0);
  if (fr <= 1000 && n0 < 400) {
    int b = rowi >> 10;
    const float* wv = wav + (size_t)b * 160000;
    int sbase = fr * 160 + n0 - 200;
    float x0, x1, x2, x3, x4, x5, x6, x7;
    if (sbase >= 0 && sbase + 7 < 160000) {
      float4 a0 = *(const float4*)&wv[sbase];
      float4 a1 = *(const float4*)&wv[sbase + 4];
      x0 = a0.x; x1 = a0.y; x2 = a0.z; x3 = a0.w;
      x4 = a1.x; x5 = a1.y; x6 = a1.z; x7 = a1.w;
    } else {
      x0 = wv[reflect_idx(sbase)];
      x1 = wv[reflect_idx(sbase + 1)];
      x2 = wv[reflect_idx(sbase + 2)];
      x3 = wv[reflect_idx(sbase + 3)];
      x4 = wv[reflect_idx(sbase + 4)];
      x5 = wv[reflect_idx(sbase + 5)];
      x6 = wv[reflect_idx(sbase + 6)];
      x7 = wv[reflect_idx(sbase + 7)];
    }
    const float* w = ws + OFF_WIN + n0;
    pk.x = (u32)f2bf(x0 * w[0]) | ((u32)f2bf(x1 * w[1]) << 16);
    pk.y = (u32)f2bf(x2 * w[2]) | ((u32)f2bf(x3 * w[3]) << 16);
    pk.z = (u32)f2bf(x4 * w[4]) | ((u32)f2bf(x5 * w[5]) << 16);
    pk.w = (u32)f2bf(x6 * w[6]) | ((u32)f2bf(x7 * w[7]) << 16);
  }
  *(uint4*)(AG + (size_t)rowi * 416 + n0) = pk;
}

// One block = 128 frames of one batch row; 8 waves as 2M x 4N.
// GEMM1: A[128x416] x B[416x512] -> X re/im; P = re^2+im^2 (bf16, LDS);
// GEMM2: P[128x256] x FB[256x64] (FB read per-lane from global) -> mel^T -> store.
// LDS per buf: A-slice 8 chunks + B-tile 32 chunks, 1KB each = 40KB; dbuf = 80KB.
#define LDS_BUF 40960
__global__ __launch_bounds__(512, 2) void k_gemm(const float* __restrict__ ws,
                                                 const u16* __restrict__ AG,
                                                 float* __restrict__ mel) {
  extern __shared__ char sm[];
  const char* Bg = (const char*)(ws + OFF_BG);
  const u16* FBg = (const u16*)(ws + OFF_FBG);  // [64 mel][264]
  int tid = threadIdx.x, wid = tid >> 6, lane = tid & 63;
  int wm = wid >> 2, wn = wid & 3;
  int bx = blockIdx.x, b = blockIdx.y;
  const char* Ab = (const char*)(AG + ((size_t)b * 1024 + bx * 128) * 416);  // 832B row stride

  // stage ktile kt: chunks 0..7 = A (kq = c>>1, rowhalf = c&1), 8..39 = B
#define STAGE(kt, buf)                                                         \
  for (int c = wid; c < 40; c += 8) {                                          \
    if (c < 8) {                                                               \
      int kq = c >> 1, rh = c & 1;                                             \
      g2l16(Ab + (size_t)(rh * 64 + lane) * 832 + (kt) * 64 + kq * 16,         \
            (buf) + c * 1024);                                                 \
    } else {                                                                   \
      g2l16(Bg + (kt) * 32768 + (c - 8) * 1024 + lane * 16, (buf) + c * 1024); \
    }                                                                          \
  }

  STAGE(0, sm);
  __syncthreads();

  f32x4 acc[4][8];
  const f32x4 zf = {0.0f, 0.0f, 0.0f, 0.0f};
#pragma unroll
  for (int mi = 0; mi < 4; ++mi)
#pragma unroll
    for (int nf = 0; nf < 8; ++nf) acc[mi][nf] = zf;

  for (int kt = 0; kt < 13; ++kt) {
    char* cur = sm + (kt & 1) * LDS_BUF;
    if (kt < 12) {
      char* nxt = sm + ((kt + 1) & 1) * LDS_BUF;
      STAGE(kt + 1, nxt);
    }
    bf16x8 af[4], bfr[8];
#pragma unroll
    for (int mi = 0; mi < 4; ++mi)
      af[mi] = *(const bf16x8*)(cur + (lane >> 4) * 2048 +
                                (wm * 64 + mi * 16 + (lane & 15)) * 16);
#pragma unroll
    for (int nf = 0; nf < 8; ++nf)
      bfr[nf] = *(const bf16x8*)(cur + 8192 + (wn * 8 + nf) * 1024 + lane * 16);
#pragma unroll
    for (int mi = 0; mi < 4; ++mi)
#pragma unroll
      for (int nf = 0; nf < 8; ++nf)
        acc[mi][nf] = __builtin_amdgcn_mfma_f32_16x16x32_bf16(af[mi], bfr[nf], acc[mi][nf], 0, 0, 0);
    __syncthreads();
  }

  // ---- P = re^2+im^2 (bf16) @ LDS 0 ----
  u16* P = (u16*)sm;  // [128][264]
#pragma unroll
  for (int mi = 0; mi < 4; ++mi)
#pragma unroll
    for (int i = 0; i < 4; ++i)
#pragma unroll
      for (int r = 0; r < 4; ++r) {
        int row = wm * 64 + mi * 16 + (lane >> 4) * 4 + r;  // frame
        int bin = wn * 64 + i * 16 + (lane & 15);           // freq bin
        float re = acc[mi][2 * i][r], im = acc[mi][2 * i + 1][r];
        P[row * 264 + bin] = f2bf(re * re + im * im);
      }
  __syncthreads();

  // ---- GEMM2: wave w owns frames [w*16, w*16+16); FB fragments from global ----
  f32x4 macc[4];
#pragma unroll
  for (int nf = 0; nf < 4; ++nf) macc[nf] = zf;
  for (int kt = 0; kt < 8; ++kt) {
    int krow = kt * 32 + (lane >> 4) * 8;
    bf16x8 pa = *(const bf16x8*)&P[(wid * 16 + (lane & 15)) * 264 + krow];
#pragma unroll
    for (int nf = 0; nf < 4; ++nf) {
      bf16x8 pb = *(const bf16x8*)&FBg[(nf * 16 + (lane & 15)) * 264 + krow];
      macc[nf] = __builtin_amdgcn_mfma_f32_16x16x32_bf16(pa, pb, macc[nf], 0, 0, 0);
    }
  }
  __syncthreads();

  // ---- transpose via LDS, coalesced store ----
  float* Tld = (float*)sm;  // [64 mel][132]
#pragma unroll
  for (int nf = 0; nf < 4; ++nf)
#pragma unroll
    for (int r = 0; r < 4; ++r) {
      int m = nf * 16 + (lane & 15);
      int tr = wid * 16 + (lane >> 4) * 4 + r;
      Tld[m * 132 + tr] = macc[nf][r];
    }
  __syncthreads();

  for (int i = tid; i < 2048; i += 512) {
    int m = i >> 5, q = i & 31;
    int t = bx * 128 + q * 4;
    float4 v = *(const float4*)&Tld[m * 132 + q * 4];
    float* dst = mel + ((size_t)b * 64 + m) * MEL_STRIDE + t;
    if (t + 3 <= 1000) {
      *(float4*)dst = v;
    } else {
      if (t     <= 1000) dst[0] = v.x;
      if (t + 1 <= 1000) dst[1] = v.y;
      if (t + 2 <= 1000) dst[2] = v.z;
      if (t + 3 <= 1000) dst[3] = v.w;
    }
  }
}

// Wave-parallel EMA scan: one wave per (b,m) row, 16 t/lane, affine map compose.
__global__ __launch_bounds__(256) void k_ema(const float* __restrict__ mel,
                                             float* __restrict__ outp) {
  int wid = threadIdx.x >> 6, lane = threadIdx.x & 63;
  int row = blockIdx.x * 4 + wid;  // 0..4095
  const float* src = mel + (size_t)row * MEL_STRIDE + lane * 16;

  float x[16];
  if (lane < 63) {
    float4 v0 = *(const float4*)&src[0];
    float4 v1 = *(const float4*)&src[4];
    float4 v2 = *(const float4*)&src[8];
    float4 v3 = *(const float4*)&src[12];
    x[0] = v0.x; x[1] = v0.y; x[2] = v0.z; x[3] = v0.w;
    x[4] = v1.x; x[5] = v1.y; x[6] = v1.z; x[7] = v1.w;
    x[8] = v2.x; x[9] = v2.y; x[10] = v2.z; x[11] = v2.w;
    x[12] = v3.x; x[13] = v3.y; x[14] = v3.z; x[15] = v3.w;
#pragma unroll
    for (int i = 0; i < 16; ++i)
      if (lane * 16 + i > 1000) x[i] = 0.0f;
  } else {
#pragma unroll
    for (int i = 0; i < 16; ++i) x[i] = 0.0f;
  }

  float B = 0.0f;
#pragma unroll
  for (int i = 0; i < 16; ++i) B = fmaf(0.98f, B, 0.02f * x[i]);
  float A = 1.0f;
#pragma unroll
  for (int i = 0; i < 16; ++i) A *= 0.98f;

#pragma unroll
  for (int d = 1; d < 64; d <<= 1) {
    float Ap = __shfl_up(A, d, 64);
    float Bp = __shfl_up(B, d, 64);
    if (lane >= d) {
      B = fmaf(A, Bp, B);
      A = A * Ap;
    }
  }
  float s = __shfl_up(B, 1, 64);
  if (lane == 0) s = 0.0f;

  float* dst = outp + (size_t)row * 1001 + lane * 16;
#pragma unroll
  for (int i = 0; i < 16; ++i) {
    s = fmaf(0.98f, s, 0.02f * x[i]);
    if (lane * 16 + i <= 1000) dst[i] = log1pf(x[i] / (s + 1e-6f));
  }
}

// mfcc[b][k][t] = sum_m 10*log10(max(mel,1e-10)) * DCT[m][k]
__global__ __launch_bounds__(256) void k_mfcc(const float* __restrict__ mel,
                                              const float* __restrict__ ws,
                                              float* __restrict__ outp) {
  __shared__ float dls[64 * 20];
  const float* dct = ws + OFF_DCT;
  for (int i = threadIdx.x; i < 64 * 20; i += 256) dls[i] = dct[i];
  __syncthreads();
  int b = blockIdx.y;
  int t = blockIdx.x * 256 + threadIdx.x;
  if (t >= T_FRAMES) return;
  float acc[20];
#pragma unroll
  for (int k = 0; k < 20; ++k) acc[k] = 0.0f;
  for (int m = 0; m < 64; ++m) {
    float v = mel[((size_t)b * 64 + m) * MEL_STRIDE + t];
    float db = 10.0f * log10f(fmaxf(v, 1e-10f));
#pragma unroll
    for (int k = 0; k < 20; ++k) acc[k] = fmaf(db, dls[m * 20 + k], acc[k]);
  }
  float* o = outp + (size_t)b * 20 * 1001 + t;
#pragma unroll
  for (int k = 0; k < 20; ++k) o[(size_t)k * 1001] = acc[k];
}

extern "C" void kernel_launch(void* const* d_in, const int* in_sizes, int n_in,
                              void* d_out, int out_size, void* d_ws, size_t ws_size,
                              hipStream_t stream) {
  const float* wav = (const float*)d_in[0];
  float* out = (float*)d_out;
  float* ws = (float*)d_ws;
  u16* AG = (u16*)(ws + OFF_AG);
  float* mel = ws + OFF_MEL;

  hipFuncSetAttribute(reinterpret_cast<const void*>(k_gemm),
                      hipFuncAttributeMaxDynamicSharedMemorySize, 81920);

  hipLaunchKernelGGL(k_init, dim3(64), dim3(256), 0, stream, ws);
  hipLaunchKernelGGL(k_prep, dim3(13312), dim3(256), 0, stream, wav, ws, AG);
  hipLaunchKernelGGL(k_gemm, dim3(8, 64), dim3(512), 81920, stream, ws, AG, mel);
  hipLaunchKernelGGL(k_ema, dim3(1024), dim3(256), 0, stream, mel, out);
  hipLaunchKernelGGL(k_mfcc, dim3(4, 64), dim3(256), 0, stream, mel, ws, out + 4100096);
}

// Round 10
// 111.816 us; speedup vs baseline: 7.2072x; 1.3327x over previous
//
#include <hip/hip_runtime.h>

#define T_FRAMES 1001
#define MEL_STRIDE 1008

// ws float offsets
#define OFF_WIN 0          // [416] f32
#define OFF_DCT 416        // [64][20] f32
#define OFF_BG  1696       // u16[13 ktile][16384] twiddles, chunked (106496 f)
#define OFF_FBG 108192     // u16[64 mel][264] (8448 f)
#define OFF_MEL 13748128   // f32 [4096][1008]  (offset kept from round 9)

typedef unsigned int u32;
typedef unsigned short u16;
typedef __attribute__((ext_vector_type(8))) short bf16x8;
typedef __attribute__((ext_vector_type(4))) float f32x4;

__device__ __forceinline__ u16 f2bf(float f) {
  u32 u = __float_as_uint(f);
  u32 r = (u + 0x7FFFu + ((u >> 16) & 1u)) >> 16;
  return (u16)r;
}

__device__ __forceinline__ int reflect_idx(int g) {
  g = (g < 0) ? -g : g;
  g = (g >= 160000) ? (319998 - g) : g;
  return g;
}

// async global->LDS: 64 lanes x 16B; src per-lane, dest = uniform base + lane*16
__device__ __forceinline__ void g2l16(const void* g, void* l) {
  __builtin_amdgcn_global_load_lds(
      (const __attribute__((address_space(1))) u32*)(unsigned long long)g,
      (__attribute__((address_space(3))) u32*)(u32)(unsigned long long)l,
      16, 0, 0);
}

__global__ __launch_bounds__(256) void k_init(float* __restrict__ ws) {
  float* win = ws + OFF_WIN;
  float* dct = ws + OFF_DCT;
  u16* bg = (u16*)(ws + OFF_BG);
  u16* fbg = (u16*)(ws + OFF_FBG);
  const float W = 6.28318530717958647692f / 400.0f;
  int tid = blockIdx.x * 256 + threadIdx.x;
  int stride = gridDim.x * 256;
  for (int i = tid; i < 416; i += stride)
    win[i] = (i < 400) ? (0.5f - 0.5f * cosf((float)i * W)) : 0.0f;
  for (int i = tid; i < 64 * 20; i += stride) {
    int m = i / 20, k = i % 20;
    float v = cosf(3.14159265358979323846f / 64.0f * ((float)m + 0.5f) * (float)k) * sqrtf(2.0f / 64.0f);
    if (k == 0) v *= 0.70710678118654752440f;
    dct[i] = v;
  }
  // twiddles, chunked: u16 index = kt*16384 + g*512 + khalf*128 + c15*8 + e
  for (int i = tid; i < 13 * 16384; i += stride) {
    int kt = i >> 14;
    int r = i & 16383;
    int g = r >> 9;
    int khalf = (r >> 7) & 3;
    int c15 = (r >> 3) & 15;
    int e = r & 7;
    int col = g * 16 + c15;
    int n = kt * 32 + khalf * 8 + e;
    int bin = ((col >> 5) << 4) | (col & 15);
    int type = (col >> 4) & 1;
    float v = 0.0f;
    if (n < 400 && bin <= 200) {
      float a = (float)((n * bin) % 400) * W;
      v = type ? -sinf(a) : cosf(a);
    }
    bg[i] = f2bf(v);
  }
  // mel filterbank [mel][264], zero past bin 200
  for (int i = tid; i < 64 * 264; i += stride) {
    int m = i / 264, f = i % 264;
    float v = 0.0f;
    if (f <= 200) {
      float freq = 40.0f * (float)f;
      float m_max = 2595.0f * log10f(1.0f + 8000.0f / 700.0f);
      float ms = m_max / 65.0f;
      float fp0 = 700.0f * (powf(10.0f, (float)(m)     * ms / 2595.0f) - 1.0f);
      float fp1 = 700.0f * (powf(10.0f, (float)(m + 1) * ms / 2595.0f) - 1.0f);
      float fp2 = 700.0f * (powf(10.0f, (float)(m + 2) * ms / 2595.0f) - 1.0f);
      float dn = (freq - fp0) / (fp1 - fp0);
      float up = (fp2 - freq) / (fp2 - fp1);
      v = fmaxf(0.0f, fminf(dn, up));
    }
    fbg[i] = f2bf(v);
  }
}

// One block = 128 frames of one batch row; 8 waves as 2M x 4N.
// A built IN-KERNEL (reg-staged): issue wav loads early, window+f2bf+ds_write
// after the MFMA cluster (latency hidden under MFMAs).  B via g2l16 dbuf.
// GEMM1: A[128x416] x B[416x512] -> X re/im; P = re^2+im^2 (bf16, LDS);
// GEMM2: P[128x256] x FB[256x64] (FB per-lane from global) -> mel^T -> store.
// LDS per buf: A 8KB (8 chunks) + B 32KB (32 chunks); dbuf = 80KB.
#define LDS_BUF 40960
__global__ __launch_bounds__(512, 2) void k_gemm(const float* __restrict__ wav,
                                                 const float* __restrict__ ws,
                                                 float* __restrict__ mel) {
  extern __shared__ char sm[];
  const char* Bg = (const char*)(ws + OFF_BG);
  const u16* FBg = (const u16*)(ws + OFF_FBG);  // [64 mel][264]
  const float* win = ws + OFF_WIN;
  int tid = threadIdx.x, wid = tid >> 6, lane = tid & 63;
  int wm = wid >> 2, wn = wid & 3;
  int bx = blockIdx.x, b = blockIdx.y;
  const float* wv = wav + (size_t)b * 160000;

  // A-stage ownership: 4 lanes per frame row (coalesced 128B wav reads)
  int kq = tid & 3, rowq = tid >> 2;            // kq: which 8-sample group
  int frame = bx * 128 + rowq;
  int awoff = kq * 2048 + rowq * 16;            // == kq*2048 + rh*1024 + r63*16
  bool fvalid = (frame <= 1000);

  float ax[8];
  float4 w0, w1;

  // ---- prologue: A(kt=0) synchronous + B tile 0 async ----
  {
    int n0 = kq * 8;
    int g0 = frame * 160 + n0 - 200;
    if (fvalid) {
      if (g0 >= 0 && g0 + 7 < 160000) {
        float4 u = *(const float4*)&wv[g0];
        float4 v = *(const float4*)&wv[g0 + 4];
        ax[0] = u.x; ax[1] = u.y; ax[2] = u.z; ax[3] = u.w;
        ax[4] = v.x; ax[5] = v.y; ax[6] = v.z; ax[7] = v.w;
      } else {
#pragma unroll
        for (int e = 0; e < 8; ++e) ax[e] = wv[reflect_idx(g0 + e)];
      }
    } else {
#pragma unroll
      for (int e = 0; e < 8; ++e) ax[e] = 0.0f;
    }
    w0 = *(const float4*)&win[n0];
    w1 = *(const float4*)&win[n0 + 4];
    uint4 pk;
    pk.x = (u32)f2bf(ax[0] * w0.x) | ((u32)f2bf(ax[1] * w0.y) << 16);
    pk.y = (u32)f2bf(ax[2] * w0.z) | ((u32)f2bf(ax[3] * w0.w) << 16);
    pk.z = (u32)f2bf(ax[4] * w1.x) | ((u32)f2bf(ax[5] * w1.y) << 16);
    pk.w = (u32)f2bf(ax[6] * w1.z) | ((u32)f2bf(ax[7] * w1.w) << 16);
    *(uint4*)(sm + awoff) = pk;
  }
  for (int c = wid; c < 32; c += 8)
    g2l16(Bg + c * 1024 + lane * 16, sm + 8192 + c * 1024);
  __syncthreads();

  f32x4 acc[4][8];
  const f32x4 zf = {0.0f, 0.0f, 0.0f, 0.0f};
#pragma unroll
  for (int mi = 0; mi < 4; ++mi)
#pragma unroll
    for (int nf = 0; nf < 8; ++nf) acc[mi][nf] = zf;

  for (int kt = 0; kt < 13; ++kt) {
    char* cur = sm + (kt & 1) * LDS_BUF;
    char* nxt = sm + ((kt + 1) & 1) * LDS_BUF;
    bool pre = (kt < 12);
    // issue phase: wav loads (to regs) + win loads + B g2l16 for kt+1
    if (pre) {
      int n0 = (kt + 1) * 32 + kq * 8;
      int g0 = frame * 160 + n0 - 200;
      if (fvalid) {
        if (g0 >= 0 && g0 + 7 < 160000) {
          float4 u = *(const float4*)&wv[g0];
          float4 v = *(const float4*)&wv[g0 + 4];
          ax[0] = u.x; ax[1] = u.y; ax[2] = u.z; ax[3] = u.w;
          ax[4] = v.x; ax[5] = v.y; ax[6] = v.z; ax[7] = v.w;
        } else {
#pragma unroll
          for (int e = 0; e < 8; ++e) ax[e] = wv[reflect_idx(g0 + e)];
        }
      } else {
#pragma unroll
        for (int e = 0; e < 8; ++e) ax[e] = 0.0f;
      }
      w0 = *(const float4*)&win[n0];
      w1 = *(const float4*)&win[n0 + 4];
      for (int c = wid; c < 32; c += 8)
        g2l16(Bg + (kt + 1) * 32768 + c * 1024 + lane * 16, nxt + 8192 + c * 1024);
    }
    // compute phase
    bf16x8 af[4], bfr[8];
#pragma unroll
    for (int mi = 0; mi < 4; ++mi)
      af[mi] = *(const bf16x8*)(cur + (lane >> 4) * 2048 +
                                (wm * 64 + mi * 16 + (lane & 15)) * 16);
#pragma unroll
    for (int nf = 0; nf < 8; ++nf)
      bfr[nf] = *(const bf16x8*)(cur + 8192 + (wn * 8 + nf) * 1024 + lane * 16);
#pragma unroll
    for (int mi = 0; mi < 4; ++mi)
#pragma unroll
      for (int nf = 0; nf < 8; ++nf)
        acc[mi][nf] = __builtin_amdgcn_mfma_f32_16x16x32_bf16(af[mi], bfr[nf], acc[mi][nf], 0, 0, 0);
    // finish phase: window + convert + ds_write A(kt+1) into nxt
    if (pre) {
      uint4 pk;
      pk.x = (u32)f2bf(ax[0] * w0.x) | ((u32)f2bf(ax[1] * w0.y) << 16);
      pk.y = (u32)f2bf(ax[2] * w0.z) | ((u32)f2bf(ax[3] * w0.w) << 16);
      pk.z = (u32)f2bf(ax[4] * w1.x) | ((u32)f2bf(ax[5] * w1.y) << 16);
      pk.w = (u32)f2bf(ax[6] * w1.z) | ((u32)f2bf(ax[7] * w1.w) << 16);
      *(uint4*)(nxt + awoff) = pk;
    }
    __syncthreads();
  }

  // ---- P = re^2+im^2 (bf16) @ LDS 0 ----
  u16* P = (u16*)sm;  // [128][264]
#pragma unroll
  for (int mi = 0; mi < 4; ++mi)
#pragma unroll
    for (int i = 0; i < 4; ++i)
#pragma unroll
      for (int r = 0; r < 4; ++r) {
        int row = wm * 64 + mi * 16 + (lane >> 4) * 4 + r;  // frame
        int bin = wn * 64 + i * 16 + (lane & 15);           // freq bin
        float re = acc[mi][2 * i][r], im = acc[mi][2 * i + 1][r];
        P[row * 264 + bin] = f2bf(re * re + im * im);
      }
  __syncthreads();

  // ---- GEMM2: wave w owns frames [w*16, w*16+16); FB fragments from global ----
  f32x4 macc[4];
#pragma unroll
  for (int nf = 0; nf < 4; ++nf) macc[nf] = zf;
  for (int kt = 0; kt < 8; ++kt) {
    int krow = kt * 32 + (lane >> 4) * 8;
    bf16x8 pa = *(const bf16x8*)&P[(wid * 16 + (lane & 15)) * 264 + krow];
#pragma unroll
    for (int nf = 0; nf < 4; ++nf) {
      bf16x8 pb = *(const bf16x8*)&FBg[(nf * 16 + (lane & 15)) * 264 + krow];
      macc[nf] = __builtin_amdgcn_mfma_f32_16x16x32_bf16(pa, pb, macc[nf], 0, 0, 0);
    }
  }
  __syncthreads();

  // ---- transpose via LDS, coalesced store ----
  float* Tld = (float*)sm;  // [64 mel][132]
#pragma unroll
  for (int nf = 0; nf < 4; ++nf)
#pragma unroll
    for (int r = 0; r < 4; ++r) {
      int m = nf * 16 + (lane & 15);
      int tr = wid * 16 + (lane >> 4) * 4 + r;
      Tld[m * 132 + tr] = macc[nf][r];
    }
  __syncthreads();

  for (int i = tid; i < 2048; i += 512) {
    int m = i >> 5, q = i & 31;
    int t = bx * 128 + q * 4;
    float4 v = *(const float4*)&Tld[m * 132 + q * 4];
    float* dst = mel + ((size_t)b * 64 + m) * MEL_STRIDE + t;
    if (t + 3 <= 1000) {
      *(float4*)dst = v;
    } else {
      if (t     <= 1000) dst[0] = v.x;
      if (t + 1 <= 1000) dst[1] = v.y;
      if (t + 2 <= 1000) dst[2] = v.z;
      if (t + 3 <= 1000) dst[3] = v.w;
    }
  }
}

// Wave-parallel EMA scan: one wave per (b,m) row, 16 t/lane, affine map compose.
__global__ __launch_bounds__(256) void k_ema(const float* __restrict__ mel,
                                             float* __restrict__ outp) {
  int wid = threadIdx.x >> 6, lane = threadIdx.x & 63;
  int row = blockIdx.x * 4 + wid;  // 0..4095
  const float* src = mel + (size_t)row * MEL_STRIDE + lane * 16;

  float x[16];
  if (lane < 63) {
    float4 v0 = *(const float4*)&src[0];
    float4 v1 = *(const float4*)&src[4];
    float4 v2 = *(const float4*)&src[8];
    float4 v3 = *(const float4*)&src[12];
    x[0] = v0.x; x[1] = v0.y; x[2] = v0.z; x[3] = v0.w;
    x[4] = v1.x; x[5] = v1.y; x[6] = v1.z; x[7] = v1.w;
    x[8] = v2.x; x[9] = v2.y; x[10] = v2.z; x[11] = v2.w;
    x[12] = v3.x; x[13] = v3.y; x[14] = v3.z; x[15] = v3.w;
#pragma unroll
    for (int i = 0; i < 16; ++i)
      if (lane * 16 + i > 1000) x[i] = 0.0f;
  } else {
#pragma unroll
    for (int i = 0; i < 16; ++i) x[i] = 0.0f;
  }

  float B = 0.0f;
#pragma unroll
  for (int i = 0; i < 16; ++i) B = fmaf(0.98f, B, 0.02f * x[i]);
  float A = 1.0f;
#pragma unroll
  for (int i = 0; i < 16; ++i) A *= 0.98f;

#pragma unroll
  for (int d = 1; d < 64; d <<= 1) {
    float Ap = __shfl_up(A, d, 64);
    float Bp = __shfl_up(B, d, 64);
    if (lane >= d) {
      B = fmaf(A, Bp, B);
      A = A * Ap;
    }
  }
  float s = __shfl_up(B, 1, 64);
  if (lane == 0) s = 0.0f;

  float* dst = outp + (size_t)row * 1001 + lane * 16;
#pragma unroll
  for (int i = 0; i < 16; ++i) {
    s = fmaf(0.98f, s, 0.02f * x[i]);
    if (lane * 16 + i <= 1000) dst[i] = log1pf(x[i] / (s + 1e-6f));
  }
}

// mfcc[b][k][t] = sum_m 10*log10(max(mel,1e-10)) * DCT[m][k]
__global__ __launch_bounds__(256) void k_mfcc(const float* __restrict__ mel,
                                              const float* __restrict__ ws,
                                              float* __restrict__ outp) {
  __shared__ float dls[64 * 20];
  const float* dct = ws + OFF_DCT;
  for (int i = threadIdx.x; i < 64 * 20; i += 256) dls[i] = dct[i];
  __syncthreads();
  int b = blockIdx.y;
  int t = blockIdx.x * 256 + threadIdx.x;
  if (t >= T_FRAMES) return;
  float acc[20];
#pragma unroll
  for (int k = 0; k < 20; ++k) acc[k] = 0.0f;
  for (int m = 0; m < 64; ++m) {
    float v = mel[((size_t)b * 64 + m) * MEL_STRIDE + t];
    float db = 10.0f * log10f(fmaxf(v, 1e-10f));
#pragma unroll
    for (int k = 0; k < 20; ++k) acc[k] = fmaf(db, dls[m * 20 + k], acc[k]);
  }
  float* o = outp + (size_t)b * 20 * 1001 + t;
#pragma unroll
  for (int k = 0; k < 20; ++k) o[(size_t)k * 1001] = acc[k];
}

extern "C" void kernel_launch(void* const* d_in, const int* in_sizes, int n_in,
                              void* d_out, int out_size, void* d_ws, size_t ws_size,
                              hipStream_t stream) {
  const float* wav = (const float*)d_in[0];
  float* out = (float*)d_out;
  float* ws = (float*)d_ws;
  float* mel = ws + OFF_MEL;

  hipFuncSetAttribute(reinterpret_cast<const void*>(k_gemm),
                      hipFuncAttributeMaxDynamicSharedMemorySize, 81920);

  hipLaunchKernelGGL(k_init, dim3(64), dim3(256), 0, stream, ws);
  hipLaunchKernelGGL(k_gemm, dim3(8, 64), dim3(512), 81920, stream, wav, ws, mel);
  hipLaunchKernelGGL(k_ema, dim3(1024), dim3(256), 0, stream, mel, out);
  hipLaunchKernelGGL(k_mfcc, dim3(4, 64), dim3(256), 0, stream, mel, ws, out + 4100096);
}

// Round 11
// 102.011 us; speedup vs baseline: 7.9000x; 1.0961x over previous
//
#include <hip/hip_runtime.h>

#define T_FRAMES 1001
#define MEL_STRIDE 1008
#define P_STRIDE 268

// ws float offsets
#define OFF_WIN 0          // [416] f32
#define OFF_DCT 416        // [64][20] f32
#define OFF_BG  1696       // u16[13 ktile][16384] twiddles, chunked (106496 f)
#define OFF_FBG 108192     // u16[64 mel][264] (8448 f)
#define OFF_MEL 13748128   // f32 [4096][1008]

typedef unsigned int u32;
typedef unsigned short u16;
typedef __attribute__((ext_vector_type(8))) short bf16x8;
typedef __attribute__((ext_vector_type(4))) float f32x4;

__device__ __forceinline__ u16 f2bf(float f) {
  u32 u = __float_as_uint(f);
  u32 r = (u + 0x7FFFu + ((u >> 16) & 1u)) >> 16;
  return (u16)r;
}

__device__ __forceinline__ int reflect_idx(int g) {
  g = (g < 0) ? -g : g;
  g = (g >= 160000) ? (319998 - g) : g;
  return g;
}

__global__ __launch_bounds__(256) void k_init(float* __restrict__ ws) {
  float* win = ws + OFF_WIN;
  float* dct = ws + OFF_DCT;
  u16* bg = (u16*)(ws + OFF_BG);
  u16* fbg = (u16*)(ws + OFF_FBG);
  const float W = 6.28318530717958647692f / 400.0f;
  int tid = blockIdx.x * 256 + threadIdx.x;
  int stride = gridDim.x * 256;
  for (int i = tid; i < 416; i += stride)
    win[i] = (i < 400) ? (0.5f - 0.5f * cosf((float)i * W)) : 0.0f;
  for (int i = tid; i < 64 * 20; i += stride) {
    int m = i / 20, k = i % 20;
    float v = cosf(3.14159265358979323846f / 64.0f * ((float)m + 0.5f) * (float)k) * sqrtf(2.0f / 64.0f);
    if (k == 0) v *= 0.70710678118654752440f;
    dct[i] = v;
  }
  // twiddles, chunked: u16 index = kt*16384 + g*512 + khalf*128 + c15*8 + e
  for (int i = tid; i < 13 * 16384; i += stride) {
    int kt = i >> 14;
    int r = i & 16383;
    int g = r >> 9;
    int khalf = (r >> 7) & 3;
    int c15 = (r >> 3) & 15;
    int e = r & 7;
    int col = g * 16 + c15;
    int n = kt * 32 + khalf * 8 + e;
    int bin = ((col >> 5) << 4) | (col & 15);
    int type = (col >> 4) & 1;
    float v = 0.0f;
    if (n < 400 && bin <= 200) {
      float a = (float)((n * bin) % 400) * W;
      v = type ? -sinf(a) : cosf(a);
    }
    bg[i] = f2bf(v);
  }
  // mel filterbank [mel][264], zero past bin 200
  for (int i = tid; i < 64 * 264; i += stride) {
    int m = i / 264, f = i % 264;
    float v = 0.0f;
    if (f <= 200) {
      float freq = 40.0f * (float)f;
      float m_max = 2595.0f * log10f(1.0f + 8000.0f / 700.0f);
      float ms = m_max / 65.0f;
      float fp0 = 700.0f * (powf(10.0f, (float)(m)     * ms / 2595.0f) - 1.0f);
      float fp1 = 700.0f * (powf(10.0f, (float)(m + 1) * ms / 2595.0f) - 1.0f);
      float fp2 = 700.0f * (powf(10.0f, (float)(m + 2) * ms / 2595.0f) - 1.0f);
      float dn = (freq - fp0) / (fp1 - fp0);
      float up = (fp2 - freq) / (fp2 - fp1);
      v = fmaxf(0.0f, fminf(dn, up));
    }
    fbg[i] = f2bf(v);
  }
}

// One block = 128 frames of one batch row; 8 waves as 2M x 4N.
// A (windowed frames, bf16) built ONCE into LDS for all 13 ktiles (104 KB).
// K-loop: ZERO barriers, zero LDS writes — B fragments read global->reg
// (coalesced 1KB chunks, L2-resident), af from LDS.
// P = re^2+im^2 (bf16, LDS); GEMM2 with swapped operands -> D[m][frame],
// stored direct to mel (no transpose pass).
__global__ __launch_bounds__(512, 2) void k_gemm(const float* __restrict__ wav,
                                                 const float* __restrict__ ws,
                                                 float* __restrict__ mel) {
  extern __shared__ char sm[];  // A: [13 kt][8192 B]
  const char* Bg = (const char*)(ws + OFF_BG);
  const u16* FBg = (const u16*)(ws + OFF_FBG);  // [64 mel][264]
  const float* win = ws + OFF_WIN;
  int tid = threadIdx.x, wid = tid >> 6, lane = tid & 63;
  int wm = wid >> 2, wn = wid & 3;
  int bx = blockIdx.x, b = blockIdx.y;
  const float* wv = wav + (size_t)b * 160000;

  // ---- A build, all 13 ktiles: 4 lanes per frame row (coalesced reads) ----
  {
    int kq = tid & 3, rowq = tid >> 2;
    int frame = bx * 128 + rowq;
    bool fvalid = (frame <= 1000);
#pragma unroll 4
    for (int kt = 0; kt < 13; ++kt) {
      int n0 = kt * 32 + kq * 8;
      int g0 = frame * 160 + n0 - 200;
      float ax[8];
      if (fvalid) {
        if (g0 >= 0 && g0 + 7 < 160000) {
          float4 u = *(const float4*)&wv[g0];
          float4 v = *(const float4*)&wv[g0 + 4];
          ax[0] = u.x; ax[1] = u.y; ax[2] = u.z; ax[3] = u.w;
          ax[4] = v.x; ax[5] = v.y; ax[6] = v.z; ax[7] = v.w;
        } else {
#pragma unroll
          for (int e = 0; e < 8; ++e) ax[e] = wv[reflect_idx(g0 + e)];
        }
      } else {
#pragma unroll
        for (int e = 0; e < 8; ++e) ax[e] = 0.0f;
      }
      float4 w0 = *(const float4*)&win[n0];
      float4 w1 = *(const float4*)&win[n0 + 4];
      uint4 pk;
      pk.x = (u32)f2bf(ax[0] * w0.x) | ((u32)f2bf(ax[1] * w0.y) << 16);
      pk.y = (u32)f2bf(ax[2] * w0.z) | ((u32)f2bf(ax[3] * w0.w) << 16);
      pk.z = (u32)f2bf(ax[4] * w1.x) | ((u32)f2bf(ax[5] * w1.y) << 16);
      pk.w = (u32)f2bf(ax[6] * w1.z) | ((u32)f2bf(ax[7] * w1.w) << 16);
      *(uint4*)(sm + kt * 8192 + kq * 2048 + rowq * 16) = pk;
    }
  }
  __syncthreads();

  // ---- GEMM1: barrier-free K-loop; wave (wm,wn) owns rows wm*64+64, cols wn*128+128
  f32x4 acc[4][8];
  const f32x4 zf = {0.0f, 0.0f, 0.0f, 0.0f};
#pragma unroll
  for (int mi = 0; mi < 4; ++mi)
#pragma unroll
    for (int nf = 0; nf < 8; ++nf) acc[mi][nf] = zf;

#pragma unroll
  for (int kt = 0; kt < 13; ++kt) {
    bf16x8 bfr[8], af[4];
#pragma unroll
    for (int nf = 0; nf < 8; ++nf)
      bfr[nf] = *(const bf16x8*)(Bg + kt * 32768 + (wn * 8 + nf) * 1024 + lane * 16);
#pragma unroll
    for (int mi = 0; mi < 4; ++mi)
      af[mi] = *(const bf16x8*)(sm + kt * 8192 + (lane >> 4) * 2048 +
                                (wm * 64 + mi * 16 + (lane & 15)) * 16);
#pragma unroll
    for (int mi = 0; mi < 4; ++mi)
#pragma unroll
      for (int nf = 0; nf < 8; ++nf)
        acc[mi][nf] = __builtin_amdgcn_mfma_f32_16x16x32_bf16(af[mi], bfr[nf], acc[mi][nf], 0, 0, 0);
  }
  __syncthreads();  // all A reads done before P overwrites the region

  // ---- P = re^2+im^2 (bf16) @ LDS 0, stride 268 ----
  u16* P = (u16*)sm;  // [128 frame][268]
#pragma unroll
  for (int mi = 0; mi < 4; ++mi)
#pragma unroll
    for (int i = 0; i < 4; ++i)
#pragma unroll
      for (int r = 0; r < 4; ++r) {
        int row = wm * 64 + mi * 16 + (lane >> 4) * 4 + r;  // frame
        int bin = wn * 64 + i * 16 + (lane & 15);           // freq bin
        float re = acc[mi][2 * i][r], im = acc[mi][2 * i + 1][r];
        P[row * P_STRIDE + bin] = f2bf(re * re + im * im);
      }
  __syncthreads();

  // ---- GEMM2 (operands swapped): D[m][frame] = FB[m][bins] x P^T[bins][frame]
  // wave wid owns frames [wid*16, wid*16+16); nf = mel group.
  f32x4 macc[4];
#pragma unroll
  for (int nf = 0; nf < 4; ++nf) macc[nf] = zf;
#pragma unroll
  for (int kt = 0; kt < 8; ++kt) {
    int krow = kt * 32 + (lane >> 4) * 8;
    bf16x8 pb = *(const bf16x8*)&P[(wid * 16 + (lane & 15)) * P_STRIDE + krow];
#pragma unroll
    for (int nf = 0; nf < 4; ++nf) {
      bf16x8 fa = *(const bf16x8*)&FBg[(nf * 16 + (lane & 15)) * 264 + krow];
      macc[nf] = __builtin_amdgcn_mfma_f32_16x16x32_bf16(fa, pb, macc[nf], 0, 0, 0);
    }
  }

  // ---- direct store: D col = frame, row = m (64B-contiguous per 16 lanes) ----
  int t = bx * 128 + wid * 16 + (lane & 15);
  if (t <= 1000) {
#pragma unroll
    for (int nf = 0; nf < 4; ++nf)
#pragma unroll
      for (int r = 0; r < 4; ++r) {
        int m = nf * 16 + (lane >> 4) * 4 + r;
        mel[((size_t)b * 64 + m) * MEL_STRIDE + t] = macc[nf][r];
      }
  }
}

// Wave-parallel EMA scan: one wave per (b,m) row, 16 t/lane, affine map compose.
__global__ __launch_bounds__(256) void k_ema(const float* __restrict__ mel,
                                             float* __restrict__ outp) {
  int wid = threadIdx.x >> 6, lane = threadIdx.x & 63;
  int row = blockIdx.x * 4 + wid;  // 0..4095
  const float* src = mel + (size_t)row * MEL_STRIDE + lane * 16;

  float x[16];
  if (lane < 63) {
    float4 v0 = *(const float4*)&src[0];
    float4 v1 = *(const float4*)&src[4];
    float4 v2 = *(const float4*)&src[8];
    float4 v3 = *(const float4*)&src[12];
    x[0] = v0.x; x[1] = v0.y; x[2] = v0.z; x[3] = v0.w;
    x[4] = v1.x; x[5] = v1.y; x[6] = v1.z; x[7] = v1.w;
    x[8] = v2.x; x[9] = v2.y; x[10] = v2.z; x[11] = v2.w;
    x[12] = v3.x; x[13] = v3.y; x[14] = v3.z; x[15] = v3.w;
#pragma unroll
    for (int i = 0; i < 16; ++i)
      if (lane * 16 + i > 1000) x[i] = 0.0f;
  } else {
#pragma unroll
    for (int i = 0; i < 16; ++i) x[i] = 0.0f;
  }

  float B = 0.0f;
#pragma unroll
  for (int i = 0; i < 16; ++i) B = fmaf(0.98f, B, 0.02f * x[i]);
  float A = 1.0f;
#pragma unroll
  for (int i = 0; i < 16; ++i) A *= 0.98f;

#pragma unroll
  for (int d = 1; d < 64; d <<= 1) {
    float Ap = __shfl_up(A, d, 64);
    float Bp = __shfl_up(B, d, 64);
    if (lane >= d) {
      B = fmaf(A, Bp, B);
      A = A * Ap;
    }
  }
  float s = __shfl_up(B, 1, 64);
  if (lane == 0) s = 0.0f;

  float* dst = outp + (size_t)row * 1001 + lane * 16;
#pragma unroll
  for (int i = 0; i < 16; ++i) {
    s = fmaf(0.98f, s, 0.02f * x[i]);
    if (lane * 16 + i <= 1000) dst[i] = log1pf(x[i] / (s + 1e-6f));
  }
}

// mfcc[b][k][t] = sum_m 10*log10(max(mel,1e-10)) * DCT[m][k]
__global__ __launch_bounds__(256) void k_mfcc(const float* __restrict__ mel,
                                              const float* __restrict__ ws,
                                              float* __restrict__ outp) {
  __shared__ float dls[64 * 20];
  const float* dct = ws + OFF_DCT;
  for (int i = threadIdx.x; i < 64 * 20; i += 256) dls[i] = dct[i];
  __syncthreads();
  int b = blockIdx.y;
  int t = blockIdx.x * 256 + threadIdx.x;
  if (t >= T_FRAMES) return;
  float acc[20];
#pragma unroll
  for (int k = 0; k < 20; ++k) acc[k] = 0.0f;
  for (int m = 0; m < 64; ++m) {
    float v = mel[((size_t)b * 64 + m) * MEL_STRIDE + t];
    float db = 10.0f * log10f(fmaxf(v, 1e-10f));
#pragma unroll
    for (int k = 0; k < 20; ++k) acc[k] = fmaf(db, dls[m * 20 + k], acc[k]);
  }
  float* o = outp + (size_t)b * 20 * 1001 + t;
#pragma unroll
  for (int k = 0; k < 20; ++k) o[(size_t)k * 1001] = acc[k];
}

extern "C" void kernel_launch(void* const* d_in, const int* in_sizes, int n_in,
                              void* d_out, int out_size, void* d_ws, size_t ws_size,
                              hipStream_t stream) {
  const float* wav = (const float*)d_in[0];
  float* out = (float*)d_out;
  float* ws = (float*)d_ws;
  float* mel = ws + OFF_MEL;

  hipFuncSetAttribute(reinterpret_cast<const void*>(k_gemm),
                      hipFuncAttributeMaxDynamicSharedMemorySize, 106496);

  hipLaunchKernelGGL(k_init, dim3(64), dim3(256), 0, stream, ws);
  hipLaunchKernelGGL(k_gemm, dim3(8, 64), dim3(512), 106496, stream, wav, ws, mel);
  hipLaunchKernelGGL(k_ema, dim3(1024), dim3(256), 0, stream, mel, out);
  hipLaunchKernelGGL(k_mfcc, dim3(4, 64), dim3(256), 0, stream, mel, ws, out + 4100096);
}